// Round 10
// baseline (117.817 us; speedup 1.0000x reference)
//
#include <hip/hip_runtime.h>

// InvariantPolynomial: out = sum_e xl[oi[e]] * xr[e] * f(|pos_e|)
// Factored: out = sum_n xl[n] * S[n], S[n] = sum_{e: oi[e]=n} xr[e]*f(d_e).
// R10: scatter-atomic pipeline -- kills the oi->xl dependent gather chain.
//  K1 build_lut: 2048-entry LUT + zero S (500KB) + zero out
//  K2 scatter:   stream pos/xr/oi (normal loads; NT was -11us, R9 lesson),
//                fire-and-forget atomicAdd into S (no reduce, no epilogue)
//  K3 dot:       xl . S, 64 blocks, double partials, one atomic each
// ws layout: [0,8KB) float LUT; [8KB, 8KB+4*N) float S.  (~508KB)

#define TN    2048
#define DMAXF 5.0f
#define TPB   256
#define EPT   8
#define TILE  (TPB * EPT)   // 2048 edges per block

// 1/sqrt(E[silu(z)^2]); matched reference exactly (absmax ~0, R1-R9)
__device__ __constant__ float kSiluCst = 1.6765581f;

__global__ __launch_bounds__(256) void build_lut_kernel(
    const float* __restrict__ W1, const float* __restrict__ W2,
    float* __restrict__ table, float* __restrict__ S, int N,
    float* __restrict__ out)
{
    int t = blockIdx.x * 256 + threadIdx.x;          // 65536 threads
    if (t == 0) out[0] = 0.0f;                        // replay-safe reset

    {   // zero S (fp32), vectorized; N=125000 -> 31250 float4, no tail
        float4* S4 = (float4*)S;
        int n4 = N >> 2;
        for (int i = t; i < n4; i += gridDim.x * 256)
            S4[i] = make_float4(0.f, 0.f, 0.f, 0.f);
        for (int i = (n4 << 2) + t; i < N; i += gridDim.x * 256)
            S[i] = 0.0f;
    }

    // 32 lanes per LUT entry: lane k in [0,30) computes hidden unit k.
    int entry = t >> 5;
    int k = t & 31;
    int kk = (k < 30) ? k : 29;

    float d  = (float)entry * (DMAXF / (float)TN);
    float t6 = 6.0f * d;                      // gaussian centers at t6 = 1..20
    const float w1scale = 1.0f / (1.12f * sqrtf(20.0f));

    float a = 0.0f;
    #pragma unroll
    for (int j = 0; j < 20; ++j) {
        float df = t6 - (float)(j + 1);
        float e  = __expf(-df * df);
        a = fmaf(e * w1scale, W1[j * 30 + kk], a);
    }
    float s = a / (1.0f + __expf(-a));        // silu

    float w2s = 0.0f;
    #pragma unroll
    for (int c = 0; c < 5; ++c) w2s += W2[kk * 5 + c];

    float contrib = (k < 30) ? s * w2s * (kSiluCst / sqrtf(30.0f)) : 0.0f;

    #pragma unroll
    for (int m = 16; m > 0; m >>= 1) contrib += __shfl_xor(contrib, m, 32);

    if (k == 0 && entry < TN) table[entry] = contrib;
}

__global__ __launch_bounds__(TPB) void scatter_kernel(
    const float* __restrict__ pos, const float* __restrict__ xr,
    const int* __restrict__ oi, const float* __restrict__ table,
    float* __restrict__ S, int E)
{
    __shared__ float lut[TN];

    const int tid = threadIdx.x;

    {   // stage 8KB LUT (2 float4/thread; table is L2/L3-hot)
        const float4* t4 = (const float4*)table;
        float4* l4 = (float4*)lut;
        l4[tid]       = t4[tid];
        l4[tid + TPB] = t4[tid + TPB];
    }
    __syncthreads();

    const float scale = (float)TN / DMAXF;
    const float umax  = (float)(TN - 1) - 1e-3f;

    const long tile0 = (long)blockIdx.x * TILE;
    const int  rem   = (int)min((long)TILE, (long)E - tile0);
    const int  e0    = tid * EPT;

    if (e0 + EPT <= rem) {
        const long g0 = tile0 + e0;
        const float4* p4 = (const float4*)(pos + g0 * 3);
        float4 P0 = p4[0], P1 = p4[1], P2 = p4[2], P3 = p4[3], P4 = p4[4], P5 = p4[5];
        const float4* x4 = (const float4*)(xr + g0);
        float4 X0 = x4[0], X1 = x4[1];
        const int4* o4 = (const int4*)(oi + g0);
        int4 O0 = o4[0], O1 = o4[1];

        float px[EPT] = {P0.x, P0.w, P1.z, P2.y, P3.x, P3.w, P4.z, P5.y};
        float py[EPT] = {P0.y, P1.x, P1.w, P2.z, P3.y, P4.x, P4.w, P5.z};
        float pz[EPT] = {P0.z, P1.y, P2.x, P2.w, P3.z, P4.y, P5.x, P5.w};
        float xrv[EPT] = {X0.x, X0.y, X0.z, X0.w, X1.x, X1.y, X1.z, X1.w};
        int   ov[EPT]  = {O0.x, O0.y, O0.z, O0.w, O1.x, O1.y, O1.z, O1.w};

        #pragma unroll
        for (int j = 0; j < EPT; ++j) {
            float d  = sqrtf(fmaf(px[j], px[j], fmaf(py[j], py[j], pz[j] * pz[j])));
            float u  = fminf(d * scale, umax);
            int   i0 = (int)u;
            float fr = u - (float)i0;
            float f  = fmaf(fr, lut[i0 + 1] - lut[i0], lut[i0]);
            atomicAdd(&S[ov[j]], f * xrv[j]);   // fire-and-forget: no dependent load
        }
    } else if (e0 < rem) {
        for (int j = 0; j < EPT && e0 + j < rem; ++j) {
            long  ge = tile0 + e0 + j;
            float x = pos[3 * ge], y = pos[3 * ge + 1], z = pos[3 * ge + 2];
            float d  = sqrtf(fmaf(x, x, fmaf(y, y, z * z)));
            float u  = fminf(d * scale, umax);
            int   i0 = (int)u;
            float fr = u - (float)i0;
            float f  = fmaf(fr, lut[i0 + 1] - lut[i0], lut[i0]);
            atomicAdd(&S[oi[ge]], f * xr[ge]);
        }
    }
}

__global__ __launch_bounds__(256) void dot_kernel(
    const float* __restrict__ xl, const float* __restrict__ S,
    float* __restrict__ out, int N)
{
    __shared__ double swv[4];
    double acc = 0.0;
    const int stride = gridDim.x * 256;
    for (int i = blockIdx.x * 256 + threadIdx.x; i < N; i += stride)
        acc += (double)(xl[i] * S[i]);

    #pragma unroll
    for (int off = 32; off > 0; off >>= 1) acc += __shfl_down(acc, off);
    int lane = threadIdx.x & 63, wv = threadIdx.x >> 6;
    if (lane == 0) swv[wv] = acc;
    __syncthreads();
    if (threadIdx.x == 0) {
        double bsum = (swv[0] + swv[1]) + (swv[2] + swv[3]);
        atomicAdd(out, (float)bsum);            // 64 atomics: negligible
    }
}

extern "C" void kernel_launch(void* const* d_in, const int* in_sizes, int n_in,
                              void* d_out, int out_size, void* d_ws, size_t ws_size,
                              hipStream_t stream) {
    const float* pos = (const float*)d_in[0];   // [E,3]
    const float* xr  = (const float*)d_in[1];   // [E,1]
    const float* xl  = (const float*)d_in[2];   // [N,1]
    const float* W1  = (const float*)d_in[3];   // [20,30]
    const float* W2  = (const float*)d_in[4];   // [30,5]
    const int*   oi  = (const int*)d_in[5];     // [E]
    float* out = (float*)d_out;

    int E = in_sizes[1];
    int N = in_sizes[2];

    float* table = (float*)d_ws;
    float* S     = (float*)((char*)d_ws + (size_t)TN * sizeof(float));

    int nblk = (E + TILE - 1) / TILE;           // 977 for E=2M

    hipLaunchKernelGGL(build_lut_kernel, dim3((TN * 32) / 256), dim3(256), 0, stream,
                       W1, W2, table, S, N, out);
    hipLaunchKernelGGL(scatter_kernel, dim3(nblk), dim3(TPB), 0, stream,
                       pos, xr, oi, table, S, E);
    hipLaunchKernelGGL(dot_kernel, dim3(64), dim3(256), 0, stream,
                       xl, S, out, N);
}

// Round 11
// 40.529 us; speedup vs baseline: 2.9070x; 2.9070x over previous
//
#include <hip/hip_runtime.h>

// InvariantPolynomial: out = sum_e xl[oi[e]] * xr[e] * f(|pos_e|)
// f depends only on d=|pos| (sh[:,:1]==1); 2048-entry linear LUT over [0,5].
//
// R11: R6 structure (2 nodes, gather not scatter -- R10: scatter atomics =
// 105us; R9: NT loads = +11us) with the latency-hiding fix, unconfounded:
//  - EPT=4 -> 1954 blocks -> ~30.5 waves/CU (R6 was 15.3; chain cover 2x)
//  - oi loaded FIRST, xl gathers issued immediately after (vmcnt waits only
//    on O); pos/xr stream + LUT staging overlap the gather in flight
// ws layout: [0,8KB) float LUT.

#define TN    2048
#define DMAXF 5.0f
#define TPB   256
#define EPT   4
#define TILE  (TPB * EPT)   // 1024 edges per block

// 1/sqrt(E[silu(z)^2]); matched reference exactly (absmax 0.0, R1-R10)
__device__ __constant__ float kSiluCst = 1.6765581f;

__global__ __launch_bounds__(256) void build_lut_kernel(
    const float* __restrict__ W1, const float* __restrict__ W2,
    float* __restrict__ table, float* __restrict__ out)
{
    if (blockIdx.x == 0 && threadIdx.x == 0) out[0] = 0.0f;  // replay-safe reset

    // 32 lanes per LUT entry: lane k in [0,30) computes hidden unit k.
    int t = blockIdx.x * 256 + threadIdx.x;
    int entry = t >> 5;
    int k = t & 31;
    int kk = (k < 30) ? k : 29;

    float d  = (float)entry * (DMAXF / (float)TN);
    float t6 = 6.0f * d;                      // gaussian centers at t6 = 1..20
    const float w1scale = 1.0f / (1.12f * sqrtf(20.0f));

    float a = 0.0f;
    #pragma unroll
    for (int j = 0; j < 20; ++j) {
        float df = t6 - (float)(j + 1);
        float e  = __expf(-df * df);
        a = fmaf(e * w1scale, W1[j * 30 + kk], a);
    }
    float s = a / (1.0f + __expf(-a));        // silu

    float w2s = 0.0f;
    #pragma unroll
    for (int c = 0; c < 5; ++c) w2s += W2[kk * 5 + c];

    float contrib = (k < 30) ? s * w2s * (kSiluCst / sqrtf(30.0f)) : 0.0f;

    #pragma unroll
    for (int m = 16; m > 0; m >>= 1) contrib += __shfl_xor(contrib, m, 32);

    if (k == 0 && entry < TN) table[entry] = contrib;
}

__global__ __launch_bounds__(TPB) void edge_sum_kernel(
    const float* __restrict__ pos, const float* __restrict__ xr,
    const float* __restrict__ xl, const int* __restrict__ oi,
    const float* __restrict__ table, float* __restrict__ out, int E)
{
    __shared__ float lut[TN];
    __shared__ double swv[TPB / 64];

    const int  tid   = threadIdx.x;
    const long tile0 = (long)blockIdx.x * TILE;
    const int  rem   = (int)min((long)TILE, (long)E - tile0);
    const int  e0    = tid * EPT;
    const bool full  = (e0 + EPT <= rem);

    // ---- oi first: start the oi->xl dependent chain before everything ----
    int4 O;
    float xlv[EPT];
    if (full) {
        const long g0 = tile0 + e0;
        O = *(const int4*)(oi + g0);
        // gathers issue as soon as O lands (only O is outstanding at waitcnt)
        xlv[0] = xl[O.x]; xlv[1] = xl[O.y]; xlv[2] = xl[O.z]; xlv[3] = xl[O.w];
    }

    // ---- stream loads: overlap with gathers in flight ----
    float4 P0, P1, P2, X;
    if (full) {
        const long g0 = tile0 + e0;
        const float4* p4 = (const float4*)(pos + g0 * 3);
        P0 = p4[0]; P1 = p4[1]; P2 = p4[2];
        X  = *(const float4*)(xr + g0);
    }

    {   // stage 8KB LUT (2 float4/thread; table is L2/L3-hot)
        const float4* t4 = (const float4*)table;
        float4* l4 = (float4*)lut;
        l4[tid]       = t4[tid];
        l4[tid + TPB] = t4[tid + TPB];
    }
    __syncthreads();

    const float scale = (float)TN / DMAXF;
    const float umax  = (float)(TN - 1) - 1e-3f;
    double acc = 0.0;

    if (full) {
        float px[EPT] = {P0.x, P0.w, P1.z, P2.y};
        float py[EPT] = {P0.y, P1.x, P1.w, P2.z};
        float pz[EPT] = {P0.z, P1.y, P2.x, P2.w};
        float xrv[EPT] = {X.x, X.y, X.z, X.w};

        float fsum = 0.0f;
        #pragma unroll
        for (int j = 0; j < EPT; ++j) {
            float d  = sqrtf(fmaf(px[j], px[j], fmaf(py[j], py[j], pz[j] * pz[j])));
            float u  = fminf(d * scale, umax);
            int   i0 = (int)u;
            float fr = u - (float)i0;
            float f  = fmaf(fr, lut[i0 + 1] - lut[i0], lut[i0]);
            fsum = fmaf(f * xrv[j], xlv[j], fsum);
        }
        acc = (double)fsum;
    } else if (e0 < rem) {
        // guarded scalar tail (last block only)
        float fsum = 0.0f;
        for (int j = 0; j < EPT && e0 + j < rem; ++j) {
            long  ge = tile0 + e0 + j;
            float x = pos[3 * ge], y = pos[3 * ge + 1], z = pos[3 * ge + 2];
            float d  = sqrtf(fmaf(x, x, fmaf(y, y, z * z)));
            float u  = fminf(d * scale, umax);
            int   i0 = (int)u;
            float fr = u - (float)i0;
            float f  = fmaf(fr, lut[i0 + 1] - lut[i0], lut[i0]);
            fsum = fmaf(f * xr[ge], xl[oi[ge]], fsum);
        }
        acc = (double)fsum;
    }

    // deterministic block reduction (wave shfl + LDS across 4 waves)
    #pragma unroll
    for (int off = 32; off > 0; off >>= 1) acc += __shfl_down(acc, off);
    int lane = tid & 63, wv = tid >> 6;
    if (lane == 0) swv[wv] = acc;
    __syncthreads();
    if (tid == 0) {
        double bsum = (swv[0] + swv[1]) + (swv[2] + swv[3]);
        atomicAdd(out, (float)bsum);   // ~1954 atomics to one line: negligible
    }
}

extern "C" void kernel_launch(void* const* d_in, const int* in_sizes, int n_in,
                              void* d_out, int out_size, void* d_ws, size_t ws_size,
                              hipStream_t stream) {
    const float* pos = (const float*)d_in[0];   // [E,3]
    const float* xr  = (const float*)d_in[1];   // [E,1]
    const float* xl  = (const float*)d_in[2];   // [N,1]
    const float* W1  = (const float*)d_in[3];   // [20,30]
    const float* W2  = (const float*)d_in[4];   // [30,5]
    const int*   oi  = (const int*)d_in[5];     // [E]
    float* out = (float*)d_out;

    int E = in_sizes[1];
    int nblk = (E + TILE - 1) / TILE;           // 1954 for E=2M

    float* table = (float*)d_ws;

    hipLaunchKernelGGL(build_lut_kernel, dim3((TN * 32) / 256), dim3(256), 0, stream,
                       W1, W2, table, out);
    hipLaunchKernelGGL(edge_sum_kernel, dim3(nblk), dim3(TPB), 0, stream,
                       pos, xr, xl, oi, table, out, E);
}